// Round 9
// baseline (144.305 us; speedup 1.0000x reference)
//
#include <hip/hip_runtime.h>
#include <hip/hip_bf16.h>
#include <math.h>

#define B_ 8
#define T_ 2048
#define C_ 1024
#define H_ 64
#define M_ (B_*T_)   // 16384 rows

typedef __attribute__((ext_vector_type(8))) short bf16x8;
typedef __attribute__((ext_vector_type(4))) float floatx4;

// fp32 -> bf16 round-to-nearest-even (cold paths)
static __device__ __forceinline__ unsigned short f2bf(float f) {
    union { float f; unsigned u; } v; v.f = f;
    unsigned r = v.u + 0x7fffu + ((v.u >> 16) & 1u);
    return (unsigned short)(r >> 16);
}
// fp32 -> bf16 round-half-up (2 VALU) for hot paths
static __device__ __forceinline__ unsigned short f2bf_fast(float f) {
    union { float f; unsigned u; } v; v.f = f;
    return (unsigned short)((v.u + 0x8000u) >> 16);
}
// pack two fp32 -> bf16 pair [hi|lo] in 3 VALU (add, add, v_perm)
static __device__ __forceinline__ unsigned pk2h(float lo, float hi) {
    union { float f; unsigned u; } a, b; a.f = lo; b.f = hi;
    return __builtin_amdgcn_perm(b.u + 0x8000u, a.u + 0x8000u, 0x07060302u);
}
static __device__ __forceinline__ bf16x8 cvt8(float4 f0, float4 f1) {
    union { uint4 u; bf16x8 v; } r;
    r.u.x = pk2h(f0.x, f0.y); r.u.y = pk2h(f0.z, f0.w);
    r.u.z = pk2h(f1.x, f1.y); r.u.w = pk2h(f1.z, f1.w);
    return r.v;
}

#define MFMA(a,b,c) __builtin_amdgcn_mfma_f32_16x16x32_bf16((a),(b),(c),0,0,0)

// ---------------------------------------------------------------------------
// Kernel 0: W prep -> wt2 in MFMA B-fragment order.
// wt2 flat: ((tile*32 + kchunk)*64 + lane)*8; tile=0..11 (16 cols, q|k|v),
// kchunk=0..31 (32 k each); lane frag [col=l15][k=quad*8+j].
// q-columns (tiles 0..3) pre-scaled by 0.125.
// ---------------------------------------------------------------------------
__global__ __launch_bounds__(256) void wprep_kernel(
    const float* __restrict__ Wq, const float* __restrict__ Wk,
    const float* __restrict__ Wv, unsigned short* __restrict__ wt2)
{
    const int f    = blockIdx.x * 256 + threadIdx.x;  // 0..24575
    const int nt   = f >> 11;
    const int kc   = (f >> 6) & 31;
    const int lane = f & 63;
    const int l15  = lane & 15, quad = lane >> 4;
    const int col  = nt * 16 + l15;                   // 0..191
    const float* W = (col < 64) ? Wq : ((col < 128) ? Wk : Wv);
    const int   cw = col & 63;
    const float sc = (col < 64) ? 0.125f : 1.0f;
    unsigned short o[8];
    #pragma unroll
    for (int j = 0; j < 8; j++) {
        const int kk = kc * 32 + quad * 8 + j;
        o[j] = f2bf(W[(size_t)kk * 64 + cw] * sc);
    }
    *(uint4*)&wt2[(size_t)f * 8] = *(const uint4*)o;
}

// ---------------------------------------------------------------------------
// Kernel 1: QKV projection. Grid 512 x 256 thr -> 2 BLOCKS/CU so the
// per-step __syncthreads vmcnt(0) drain of one block overlaps the other
// block's compute. Block = 32 rows x 192 cols; x staged into double-
// buffered LDS [32][72] bf16 with depth-2 register prefetch; W per-wave
// direct fragment-ordered loads, depth-1.
// ---------------------------------------------------------------------------
__global__ __launch_bounds__(256) void qkv_kernel(
    const float* __restrict__ x, const unsigned short* __restrict__ wt2,
    unsigned short* __restrict__ qo, unsigned short* __restrict__ ko,
    unsigned short* __restrict__ vo)
{
    // union: xs[2][32*72] (9.2 KB) during loop; es[32][200] (12.8 KB) epilogue
    __shared__ __align__(16) unsigned short smem[32 * 200];
    #define XS_(buf) (smem + (buf) * 2304)

    const int t    = threadIdx.x;
    const int w    = t >> 6;
    const int lane = t & 63;
    const int l15  = lane & 15;
    const int quad = lane >> 4;
    const int r0   = blockIdx.x * 32;

    // staging map: row = t>>3 (0..31), group g0 = t&7 (8 floats)
    const int srow = t >> 3;
    const int g0   = t & 7;
    const float* xrow = x + (size_t)(r0 + srow) * C_;

    // W pointers: wave w owns tiles w*3 .. w*3+2
    const unsigned short* wb = wt2 + (size_t)(w * 3) * 32 * 512 + lane * 8;

    floatx4 acc[2][3];
    #pragma unroll
    for (int mt = 0; mt < 2; mt++)
        #pragma unroll
        for (int nt = 0; nt < 3; nt++) acc[mt][nt] = (floatx4)(0.0f);

    float4 xA[2], xB[2];
    bf16x8 wcur[6], wnxt[6];

    // ---- preamble: issue x chunks 0,1 and W chunk 0; stage chunk 0 ----
    xA[0] = *(const float4*)(xrow + g0 * 8);
    xA[1] = *(const float4*)(xrow + g0 * 8 + 4);
    xB[0] = *(const float4*)(xrow + 64 + g0 * 8);
    xB[1] = *(const float4*)(xrow + 64 + g0 * 8 + 4);
    #pragma unroll
    for (int nt = 0; nt < 3; nt++)
        #pragma unroll
        for (int ks = 0; ks < 2; ks++)
            wcur[nt * 2 + ks] = *(const bf16x8*)(wb + (size_t)(nt * 32 + ks) * 512);
    *(bf16x8*)(XS_(0) + srow * 72 + g0 * 8) = cvt8(xA[0], xA[1]);
    __syncthreads();

    // step c: prefetch chunk c+2 into Xcur (freed), compute chunk c from
    // LDS(buf)+wcur, stage chunk c+1 from Xnext into LDS(buf^1), roll W.
    #define QSTEP(c, Xcur, Xnext, buf)                                         \
    {                                                                          \
        if ((c) < 14) {                                                        \
            const int k2 = ((c) + 2) * 64;                                     \
            Xcur[0] = *(const float4*)(xrow + k2 + g0 * 8);                    \
            Xcur[1] = *(const float4*)(xrow + k2 + g0 * 8 + 4);                \
        }                                                                      \
        if ((c) < 15) {                                                        \
            _Pragma("unroll")                                                  \
            for (int nt = 0; nt < 3; nt++)                                     \
                _Pragma("unroll")                                              \
                for (int ks = 0; ks < 2; ks++)                                 \
                    wnxt[nt * 2 + ks] = *(const bf16x8*)                       \
                        (wb + (size_t)(nt * 32 + 2 * ((c) + 1) + ks) * 512);   \
        }                                                                      \
        _Pragma("unroll")                                                      \
        for (int ks = 0; ks < 2; ks++) {                                       \
            bf16x8 af[2];                                                      \
            _Pragma("unroll")                                                  \
            for (int mt = 0; mt < 2; mt++)                                     \
                af[mt] = *(const bf16x8*)                                      \
                    (XS_(buf) + (mt * 16 + l15) * 72 + ks * 32 + quad * 8);    \
            _Pragma("unroll")                                                  \
            for (int mt = 0; mt < 2; mt++)                                     \
                _Pragma("unroll")                                              \
                for (int nt = 0; nt < 3; nt++)                                 \
                    acc[mt][nt] = MFMA(af[mt], wcur[nt * 2 + ks], acc[mt][nt]);\
        }                                                                      \
        if ((c) < 15) {                                                        \
            *(bf16x8*)(XS_((buf) ^ 1) + srow * 72 + g0 * 8)                    \
                = cvt8(Xnext[0], Xnext[1]);                                    \
            _Pragma("unroll")                                                  \
            for (int i = 0; i < 6; i++) wcur[i] = wnxt[i];                     \
        }                                                                      \
        __syncthreads();                                                       \
    }

    for (int cc = 0; cc < 16; cc += 2) {
        QSTEP(cc,     xA, xB, 0)
        QSTEP(cc + 1, xB, xA, 1)
    }
    #undef QSTEP

    // ---- epilogue: repack through LDS (aliases xs; loop-end barrier done) ---
    #pragma unroll
    for (int mt = 0; mt < 2; mt++)
        #pragma unroll
        for (int nt = 0; nt < 3; nt++) {
            const int col = w * 48 + nt * 16 + l15;
            #pragma unroll
            for (int r = 0; r < 4; r++)
                smem[(mt * 16 + quad * 4 + r) * 200 + col] = f2bf(acc[mt][nt][r]);
        }
    __syncthreads();

    { // q, k: [row][64] bf16 — 32 rows x 8 octs = 256 threads, one pass each
        const int row = t >> 3, oct = t & 7;
        *(uint4*)&qo[(size_t)(r0 + row) * 64 + oct * 8] =
            *(const uint4*)&smem[row * 200 + oct * 8];
        *(uint4*)&ko[(size_t)(r0 + row) * 64 + oct * 8] =
            *(const uint4*)&smem[row * 200 + 64 + oct * 8];
    }
    { // v: transposed [b][h][t] — 64 h x 4 t-groups of 8 = 256 threads
        const int h  = t >> 2;
        const int j0 = (t & 3) * 8;
        const int bb = r0 >> 11, tt = r0 & 2047;
        unsigned short tmp[8];
        #pragma unroll
        for (int j = 0; j < 8; j++) tmp[j] = smem[(j0 + j) * 200 + 128 + h];
        *(uint4*)&vo[((size_t)bb * 64 + h) * 2048 + tt + j0] = *(uint4*)tmp;
    }
    #undef XS_
}

// ---------------------------------------------------------------------------
// Kernel 2: causal flash attention with ALiBi, bf16 MFMA.
// 256 thr (4 waves); 32-row q-tile (2 row-tiles/wave); K-range split 4 ways
// across waves; per-wave private softmax state + pT region, no per-step
// barriers. NO register prefetch: __launch_bounds__(256,3) caps VGPR at 170
// -> 3 blocks/CU = 12 waves; TLP hides the K/V L2 latency instead.
// V issued right after QK^T (arrives under softmax).
// Grid 512 = 8 batches x 64 q-tiles, heavy-first.
// ---------------------------------------------------------------------------
__global__ __launch_bounds__(256, 3) void attn_kernel(
    const unsigned short* __restrict__ q,
    const unsigned short* __restrict__ k,
    const unsigned short* __restrict__ vT,
    float* __restrict__ out)
{
    // pT during loop: 4 waves x 32x72 halfs = 18432 B at offset 0.
    // merge after barrier: Omg [4][32][64] f32 = 32768 B at 0,
    //                      mlg [4][2][32]  f32 =  1024 B at 32768.
    __shared__ __align__(16) unsigned char smem[32768 + 1024];
    unsigned short* pT  = (unsigned short*)smem;
    float*          Omg = (float*)smem;
    float*          mlg = (float*)(smem + 32768);

    const int t    = threadIdx.x;
    const int w    = t >> 6;
    const int lane = t & 63;
    const int l15  = lane & 15;
    const int quad = lane >> 4;
    const int b    = blockIdx.x & 7;
    const int qt   = 63 - (blockIdx.x >> 3);   // heavy tiles first
    const int q0   = qt * 32;
    const size_t kb = (size_t)b * T_ * 64;

    // Q A-fragments for both row-tiles (scale folded into Wq)
    bf16x8 qf[2][2];
    #pragma unroll
    for (int rt = 0; rt < 2; rt++)
        #pragma unroll
        for (int ks = 0; ks < 2; ks++)
            qf[rt][ks] = *(const bf16x8*)
                &q[kb + (size_t)(q0 + rt * 16 + l15) * 64 + ks * 32 + quad * 8];

    floatx4 O[2][4];
    float mrow[2][4], lrow[2][4], igb[2][4];
    const float bs = 0.088388347648318447f;     // 2^-0.5 * 0.125
    #pragma unroll
    for (int rt = 0; rt < 2; rt++) {
        #pragma unroll
        for (int nt = 0; nt < 4; nt++) O[rt][nt] = (floatx4)(0.0f);
        #pragma unroll
        for (int r = 0; r < 4; r++) {
            mrow[rt][r] = -INFINITY; lrow[rt][r] = 0.0f;
            igb[rt][r] = (float)(q0 + rt * 16 + quad * 4 + r) * bs;
        }
    }

    const int nsteps = (q0 + 32 + 63) >> 6;
    const int ns4    = (nsteps + 3) >> 2;
    const int sBeg   = w * ns4;
    const int sEnd   = min(sBeg + ns4, nsteps);
    unsigned short* pw = pT + w * 32 * 72;

    for (int s = sBeg; s < sEnd; s++) {
        const int j0 = s * 64;

        // ---- K fragments for this step ----
        bf16x8 kf[4][2];
        #pragma unroll
        for (int nt = 0; nt < 4; nt++)
            #pragma unroll
            for (int ks = 0; ks < 2; ks++)
                kf[nt][ks] = *(const bf16x8*)
                    &k[kb + (size_t)(j0 + nt * 16 + l15) * 64 + ks * 32 + quad * 8];

        // ---- S = Q K^T for both row-tiles ----
        floatx4 sc[2][4];
        #pragma unroll
        for (int rt = 0; rt < 2; rt++)
            #pragma unroll
            for (int nt = 0; nt < 4; nt++) {
                floatx4 z = (floatx4)(0.0f);
                z = MFMA(qf[rt][0], kf[nt][0], z);
                z = MFMA(qf[rt][1], kf[nt][1], z);
                sc[rt][nt] = z;
            }

        // ---- issue V now; arrives under softmax ----
        bf16x8 vf[4][2];
        #pragma unroll
        for (int nt = 0; nt < 4; nt++)
            #pragma unroll
            for (int ks = 0; ks < 2; ks++)
                vf[nt][ks] = *(const bf16x8*)
                    &vT[((size_t)b * 64 + nt * 16 + l15) * 2048 + j0 + ks * 32 + quad * 8];

        // ---- ALiBi + causal + online softmax (deferred l-reduce) ----
        const float jbase = (float)(j0 + l15) * bs;
        #pragma unroll
        for (int rt = 0; rt < 2; rt++)
            #pragma unroll
            for (int r = 0; r < 4; r++) {
                const int   ig = q0 + rt * 16 + quad * 4 + r;
                const float c0 = jbase - igb[rt][r];
                float xv[4];
                float mloc = -INFINITY;
                #pragma unroll
                for (int nt = 0; nt < 4; nt++) {
                    const int j = j0 + nt * 16 + l15;
                    float v2 = (sc[rt][nt][r] + c0) + (float)(nt * 16) * bs;
                    if (j > ig) v2 = -INFINITY;
                    xv[nt] = v2;
                    mloc = fmaxf(mloc, v2);
                }
                #pragma unroll
                for (int off = 1; off < 16; off <<= 1)
                    mloc = fmaxf(mloc, __shfl_xor(mloc, off));
                const float mnew = fmaxf(mrow[rt][r], mloc);
                const float mq   = (mnew == -INFINITY) ? 0.0f : mnew;
                const float alpha = __expf(mrow[rt][r] - mq);
                mrow[rt][r] = mnew;
                float ps = 0.0f;
                #pragma unroll
                for (int nt = 0; nt < 4; nt++) {
                    const float p = __expf(xv[nt] - mq);
                    ps += p;
                    pw[(rt * 16 + quad * 4 + r) * 72 + nt * 16 + l15] = f2bf_fast(p);
                }
                lrow[rt][r] = lrow[rt][r] * alpha + ps;   // per-lane partial
                #pragma unroll
                for (int nt = 0; nt < 4; nt++) O[rt][nt][r] *= alpha;
            }

        // ---- O += P V  (same-wave DS in-order; no barrier) ----
        #pragma unroll
        for (int rt = 0; rt < 2; rt++) {
            const bf16x8 pf0 = *(const bf16x8*)&pw[(rt * 16 + l15) * 72 + quad * 8];
            const bf16x8 pf1 = *(const bf16x8*)&pw[(rt * 16 + l15) * 72 + 32 + quad * 8];
            #pragma unroll
            for (int nt = 0; nt < 4; nt++) {
                O[rt][nt] = MFMA(pf0, vf[nt][0], O[rt][nt]);
                O[rt][nt] = MFMA(pf1, vf[nt][1], O[rt][nt]);
            }
        }
    }

    // ---- reduce per-lane l partials across the 16 key-lanes ----
    #pragma unroll
    for (int rt = 0; rt < 2; rt++)
        #pragma unroll
        for (int r = 0; r < 4; r++)
            #pragma unroll
            for (int off = 1; off < 16; off <<= 1)
                lrow[rt][r] += __shfl_xor(lrow[rt][r], off);

    __syncthreads();   // all waves done with pT

    // ---- publish partial state ----
    #pragma unroll
    for (int rt = 0; rt < 2; rt++)
        #pragma unroll
        for (int nt = 0; nt < 4; nt++)
            #pragma unroll
            for (int r = 0; r < 4; r++)
                Omg[w * 2048 + (rt * 16 + quad * 4 + r) * 64 + nt * 16 + l15]
                    = O[rt][nt][r];
    if (l15 == 0) {
        #pragma unroll
        for (int rt = 0; rt < 2; rt++)
            #pragma unroll
            for (int r = 0; r < 4; r++) {
                mlg[w * 64 + rt * 16 + quad * 4 + r]      = mrow[rt][r];
                mlg[w * 64 + 32 + rt * 16 + quad * 4 + r] = lrow[rt][r];
            }
    }
    __syncthreads();

    // ---- merge 4 partials, write output ----
    {
        const int row = t >> 3;          // 0..31
        const int hq  = (t & 7) << 3;    // 0..56
        float mstar = -INFINITY;
        #pragma unroll
        for (int w2 = 0; w2 < 4; w2++)
            mstar = fmaxf(mstar, mlg[w2 * 64 + row]);
        floatx4 oa0 = (floatx4)(0.0f), oa1 = (floatx4)(0.0f);
        float lsum = 0.0f;
        #pragma unroll
        for (int w2 = 0; w2 < 4; w2++) {
            const float wg = __expf(mlg[w2 * 64 + row] - mstar);
            lsum += wg * mlg[w2 * 64 + 32 + row];
            oa0 += wg * *(const floatx4*)&Omg[w2 * 2048 + row * 64 + hq];
            oa1 += wg * *(const floatx4*)&Omg[w2 * 2048 + row * 64 + hq + 4];
        }
        const float inv = 1.0f / lsum;
        *(floatx4*)&out[kb + (size_t)(q0 + row) * 64 + hq]     = oa0 * inv;
        *(floatx4*)&out[kb + (size_t)(q0 + row) * 64 + hq + 4] = oa1 * inv;
    }
}

extern "C" void kernel_launch(void* const* d_in, const int* in_sizes, int n_in,
                              void* d_out, int out_size, void* d_ws, size_t ws_size,
                              hipStream_t stream) {
    (void)in_sizes; (void)n_in; (void)out_size; (void)ws_size;
    const float* x  = (const float*)d_in[0];
    const float* Wq = (const float*)d_in[1];
    const float* Wk = (const float*)d_in[2];
    const float* Wv = (const float*)d_in[3];
    float* out = (float*)d_out;

    unsigned short* wt2 = (unsigned short*)d_ws;                // [12][32][64][8]
    unsigned short* qw  = wt2 + 196608;                         // [M][64]
    unsigned short* kw  = qw + (size_t)M_ * H_;                 // [M][64]
    unsigned short* vw  = kw + (size_t)M_ * H_;                 // [B][64][2048]

    wprep_kernel<<<96, 256, 0, stream>>>(Wq, Wk, Wv, wt2);
    qkv_kernel<<<M_ / 32, 256, 0, stream>>>(x, wt2, qw, kw, vw);
    attn_kernel<<<B_ * 64, 256, 0, stream>>>(qw, kw, vw, out);
}